// Round 2
// baseline (272.718 us; speedup 1.0000x reference)
//
#include <hip/hip_runtime.h>
#include <hip/hip_bf16.h>
#include <type_traits>
#include <cstdint>

// Problem constants
#define IN_DIM   512
#define OUT_DIM  1024
#define MROWS    32768    // 8 * 4096

typedef float f32x4 __attribute__((ext_vector_type(4)));
typedef short s8vec __attribute__((ext_vector_type(8)));
typedef __bf16 b8vec __attribute__((ext_vector_type(8)));

template <typename V, typename = void>
struct mfma_ok : std::false_type {};
template <typename V>
struct mfma_ok<V, std::void_t<decltype(__builtin_amdgcn_mfma_f32_16x16x32_bf16(
    std::declval<V>(), std::declval<V>(), std::declval<f32x4>(), 0, 0, 0))>>
    : std::true_type {};
using frag_t = std::conditional_t<mfma_ok<s8vec>::value, s8vec, b8vec>;

__device__ __forceinline__ void async_copy16(void* lds, const void* g) {
    __builtin_amdgcn_global_load_lds(
        (const __attribute__((address_space(1))) void*)(uintptr_t)g,
        (__attribute__((address_space(3))) void*)(uint32_t)(uintptr_t)lds,
        16, 0, 0);
}

__device__ __forceinline__ unsigned short f2bf(float f) {
    unsigned int u = __float_as_uint(f);
    unsigned int r = (u + 0x7fffu + ((u >> 16) & 1u)) >> 16;
    return (unsigned short)r;
}

// ---------------- K1: bf16 cast + fused z@Wa / z@Wb per-block partials -----
// grid 1024 x 256; block handles 32 rows. thread: 4 cols (float4), 16 rows.
__global__ void __launch_bounds__(256) geo_k1(const float* __restrict__ x,
                                              unsigned short* __restrict__ xh,
                                              const float* __restrict__ Wa,
                                              const float* __restrict__ Wb,
                                              float* __restrict__ part) {
    const int tid  = threadIdx.x;
    const int c4   = (tid & 127) * 4;
    const int half = tid >> 7;
    const int r0   = blockIdx.x * 32 + half * 16;
    float4 s = {0.f, 0.f, 0.f, 0.f};
    for (int i = 0; i < 16; ++i) {
        const size_t base = (size_t)(r0 + i) * IN_DIM + c4;
        float4 v = *(const float4*)(x + base);
        s.x += v.x; s.y += v.y; s.z += v.z; s.w += v.w;
        ushort4 h;
        h.x = f2bf(v.x); h.y = f2bf(v.y); h.z = f2bf(v.z); h.w = f2bf(v.w);
        *(ushort4*)(xh + base) = h;
    }
    const float* wa = Wa + (size_t)c4 * 8;
    const float* wb = Wb + (size_t)c4 * 8;
    float av[8], bv[8];
#pragma unroll
    for (int r = 0; r < 8; ++r) {
        av[r] = s.x * wa[r] + s.y * wa[8 + r] + s.z * wa[16 + r] + s.w * wa[24 + r];
        bv[r] = s.x * wb[r] + s.y * wb[8 + r] + s.z * wb[16 + r] + s.w * wb[24 + r];
    }
#pragma unroll
    for (int off = 32; off; off >>= 1) {
#pragma unroll
        for (int r = 0; r < 8; ++r) {
            av[r] += __shfl_xor(av[r], off, 64);
            bv[r] += __shfl_xor(bv[r], off, 64);
        }
    }
    __shared__ float wred[4][16];
    const int lane = tid & 63, wave = tid >> 6;
    if (lane == 0) {
#pragma unroll
        for (int r = 0; r < 8; ++r) { wred[wave][r] = av[r]; wred[wave][8 + r] = bv[r]; }
    }
    __syncthreads();
    if (tid < 16)
        part[(size_t)blockIdx.x * 16 + tid] =
            wred[0][tid] + wred[1][tid] + wred[2][tid] + wred[3][tid];
}

// ---------------- K2: merged small algebra, 1 block, V in LDS --------------
__device__ __forceinline__ void mm16(float (*D)[16], float (*A)[16], float (*B)[16]) {
    const int tid = threadIdx.x;
    const int i = tid >> 4, j = tid & 15;
    float s = 0.f;
#pragma unroll
    for (int k = 0; k < 16; ++k) s += A[i][k] * B[k][j];
    __syncthreads();
    D[i][j] = s;
    __syncthreads();
}

__global__ void __launch_bounds__(256) geo_k2(const float* __restrict__ part,
                                              const float* __restrict__ La,
                                              const float* __restrict__ Ra,
                                              const float* __restrict__ Lb,
                                              const float* __restrict__ Rb,
                                              float* __restrict__ Vws,
                                              float* __restrict__ Lbp,
                                              float* __restrict__ VPws,
                                              float* __restrict__ RRws) {
    __shared__ float sV[IN_DIM][16];   // 32 KB
    __shared__ float sRb[IN_DIM][8];   // 16 KB
    __shared__ float red2[16][16];
    __shared__ float gs[16];
    __shared__ float G16[16][16], Jm[16][16];
    __shared__ float C2m[16][16], C3m[16][16], C4m[16][16];
    __shared__ float Cp[16][16], Cq[16][16];
    __shared__ float Pi[16][16], Xi[16][16], T1[16][16], T2[16][16], Ct[16][16];
    __shared__ float Zm[8][16], Em[8][16];
    const int tid = threadIdx.x;  // 256
    const int i = tid >> 4, j = tid & 15;

    // phase 0: reduce part[1024][16] -> gs (already scaled to the mean)
    {
        const int u = tid & 15, c = tid >> 4;  // 16 chunks x 64 rows
        float s = 0.f;
        for (int q = 0; q < 64; ++q) s += part[(size_t)(c * 64 + q) * 16 + u];
        red2[c][u] = s;
    }
    __syncthreads();
    if (tid < 16) {
        float s = 0.f;
#pragma unroll
        for (int c = 0; c < 16; ++c) s += red2[c][tid];
        gs[tid] = s * (1.0f / 32768.0f);
    }
    __syncthreads();

    // phase 1: build sV = [abar.*La | Ra], sRb, Lbp (global), Vws (global)
    for (int rr = 0; rr < 2; ++rr) {
        const int row = tid * 2 + rr;
#pragma unroll
        for (int r = 0; r < 8; ++r) {
            const float vl = gs[r] * La[row * 8 + r];
            const float vr = Ra[row * 8 + r];
            sV[row][r]     = vl;
            sV[row][8 + r] = vr;
            Vws[row * 16 + r]     = vl;
            Vws[row * 16 + 8 + r] = vr;
            sRb[row][r] = Rb[row * 8 + r];
            Lbp[row * 8 + r] = gs[8 + r] * Lb[row * 8 + r];
        }
    }
    __syncthreads();

    // phase 2: G16 = V^T V, Zm = Rb^T V (from LDS)
    {
        float s = 0.f;
        for (int k = 0; k < IN_DIM; ++k) s += sV[k][i] * sV[k][j];
        G16[i][j] = s;
        float jm = 0.f;
        if (i < 8 && j == i + 8) jm = 1.f;
        if (i >= 8 && j == i - 8) jm = -1.f;
        Jm[i][j] = jm;
    }
    if (tid < 128) {
        const int r = tid >> 4, u = tid & 15;
        float s = 0.f;
        for (int k = 0; k < IN_DIM; ++k) s += sRb[k][r] * sV[k][u];
        Zm[r][u] = s;
    }
    __syncthreads();

    // phase 3: RK4 core chain (16x16)
    mm16(T1, Jm, G16);  mm16(C2m, T1, Jm);
    mm16(T1, C2m, G16); mm16(C3m, T1, Jm);
    mm16(T1, C3m, G16); mm16(C4m, T1, Jm);

    const float h  = 0.125f;
    const float c1 = h, c2 = h * h * 0.5f, c3 = h * h * h * (1.f / 6.f),
                c4 = h * h * h * h * (1.f / 24.f);
    Cp[i][j] = c1 * Jm[i][j] + c2 * C2m[i][j] + c3 * C3m[i][j] + c4 * C4m[i][j];
    Cq[i][j] = c2 * Jm[i][j] + c3 * C2m[i][j] + c4 * C3m[i][j];
    Xi[i][j] = 0.f;
    __syncthreads();
    Pi[i][j] = Cp[i][j];
    __syncthreads();

    for (int it = 0; it < 7; ++it) {
        mm16(T1, Pi, G16);
        mm16(T2, T1, Cp);
        const float pij = Pi[i][j];
        Xi[i][j] += pij;
        Pi[i][j] = pij + Cp[i][j] + T2[i][j];
        __syncthreads();
    }

    mm16(T1, Cq, G16);
    mm16(T2, T1, Xi);
    Ct[i][j] = 8.f * Cq[i][j] + h * Xi[i][j] + T2[i][j];
    __syncthreads();

    // Em = Zm * Ct (8x16)
    if (tid < 128) {
        const int r = tid >> 4, u = tid & 15;
        float s = 0.f;
#pragma unroll
        for (int t = 0; t < 16; ++t) s += Zm[r][t] * Ct[t][u];
        Em[r][u] = s;
    }
    __syncthreads();

    // phase 4: VP = V @ Pi (512x16); RR[r][j] = Rb[j][r] + sum_u Em[r][u] V[j][u]
#pragma unroll
    for (int rr = 0; rr < 2; ++rr) {
        const int row = tid * 2 + rr;
        float v[16];
#pragma unroll
        for (int k = 0; k < 16; ++k) v[k] = sV[row][k];
#pragma unroll
        for (int u = 0; u < 16; ++u) {
            float s = 0.f;
#pragma unroll
            for (int k = 0; k < 16; ++k) s += v[k] * Pi[k][u];
            VPws[row * 16 + u] = s;
        }
#pragma unroll
        for (int r = 0; r < 8; ++r) {
            float s = sRb[row][r];
#pragma unroll
            for (int u = 0; u < 16; ++u) s += Em[r][u] * v[u];
            RRws[r * IN_DIM + row] = s;
        }
    }
}

// ---------------- K34: W row = U0 + (U0.VP) V^T + [0; Lbp RR] -> bf16 ------
__global__ void __launch_bounds__(256) geo_k34(const float* __restrict__ U0,
                                               const float* __restrict__ Vws,
                                               const float* __restrict__ VPws,
                                               const float* __restrict__ Lbp,
                                               const float* __restrict__ RRws,
                                               unsigned short* __restrict__ wh) {
    const int o   = blockIdx.x;
    const int tid = threadIdx.x;
    const int j0  = tid * 2;
    const float2 u0 = *(const float2*)(U0 + (size_t)o * IN_DIM + j0);

    const float* vpa = VPws + j0 * 16;
    const float* vpb = vpa + 16;
    float p[16];
#pragma unroll
    for (int u = 0; u < 16; ++u) p[u] = u0.x * vpa[u] + u0.y * vpb[u];
#pragma unroll
    for (int off = 32; off; off >>= 1) {
#pragma unroll
        for (int u = 0; u < 16; ++u) p[u] += __shfl_xor(p[u], off, 64);
    }
    __shared__ float wred[4][16];
    __shared__ float sY[16];
    const int lane = tid & 63, wave = tid >> 6;
    if (lane == 0) {
#pragma unroll
        for (int u = 0; u < 16; ++u) wred[wave][u] = p[u];
    }
    __syncthreads();
    if (tid < 16) sY[tid] = wred[0][tid] + wred[1][tid] + wred[2][tid] + wred[3][tid];
    __syncthreads();

    const float* va = Vws + j0 * 16;
    const float* vb = va + 16;
    float w0 = u0.x, w1 = u0.y;
#pragma unroll
    for (int u = 0; u < 16; ++u) {
        const float s = sY[u];
        w0 += s * va[u];
        w1 += s * vb[u];
    }
    if (o >= IN_DIM) {
        const int op = o - IN_DIM;
#pragma unroll
        for (int r = 0; r < 8; ++r) {
            const float lb = Lbp[op * 8 + r];
            w0 += lb * RRws[r * IN_DIM + j0];
            w1 += lb * RRws[r * IN_DIM + j0 + 1];
        }
    }
    ushort2 hv;
    hv.x = f2bf(w0); hv.y = f2bf(w1);
    *(ushort2*)(wh + (size_t)o * IN_DIM + j0) = hv;
}

// ---------------- K5: out = xh @ wh^T, deep-pipelined 256x256 MFMA ---------
// T3+T4 counted-vmcnt pipeline: 4 LDS slots (k-tiles, BK=32), prefetch
// distance 3 k-tiles (~3700 cy >> 900 cy HBM latency). vmcnt never drains
// to 0 in the main loop (12 loads = 3 k-tiles stay in flight); raw
// s_barrier (no compiler vmcnt(0) drain); sched_barrier(0) pins ds_reads
// inside the barrier pair so the freed slot is safe to restage.
// Per-thread gload_lds ledger: prologue 16; each iter waits vmcnt(12)
// (oldest k-tile landed), stages 4 more. Tail drains 12->8->4->0.
//
// T2 swizzle (BK=32, 4x16B chunks/row): stored chunk = c ^ ((row>>1)&3),
// applied on the GLOBAL source address (gload_lds dest stays linear);
// ds_read_b128 reads chunk (lane>>4)^(((lane&15)>>1)&3) -> bank-optimal.
//
// T1 XCD remap: 512 blocks = 8 xcds x (16 mtiles x 4 ntiles), n-fastest:
// A-tile (256 KB) reused by 4 consecutive blocks on one XCD; full B (1 MB)
// L2-resident per XCD; working set ~3 MB < 4 MB L2.
//
// Accumulation order over K identical to previous version (sequential
// 32-wide k-chunks) -> numerics unchanged.
__device__ __forceinline__ void k5_frag_loads(const char* lds, int sb, int aoff, int boff,
                                              frag_t (&a)[8], frag_t (&b)[4]) {
#pragma unroll
    for (int u = 0; u < 8; ++u)
        a[u] = *(const frag_t*)(lds + sb + aoff + u * 1024);
#pragma unroll
    for (int s = 0; s < 4; ++s)
        b[s] = *(const frag_t*)(lds + sb + boff + s * 1024);
}

template <int VM, bool DO_STAGE>
__device__ __forceinline__ void k5_step(char* lds, int t,
                                        const __hip_bfloat16* gA0, const __hip_bfloat16* gA1,
                                        const __hip_bfloat16* gB0, const __hip_bfloat16* gB1,
                                        int ldsA0, int ldsA1, int aoff, int boff,
                                        f32x4 (&acc)[8][4]) {
    if constexpr (VM == 12)     asm volatile("s_waitcnt vmcnt(12)" ::: "memory");
    else if constexpr (VM == 8) asm volatile("s_waitcnt vmcnt(8)"  ::: "memory");
    else if constexpr (VM == 4) asm volatile("s_waitcnt vmcnt(4)"  ::: "memory");
    else                        asm volatile("s_waitcnt vmcnt(0)"  ::: "memory");
    __builtin_amdgcn_s_barrier();
    __builtin_amdgcn_sched_barrier(0);

    const int sb = (t & 3) * 32768;
    frag_t a[8], b[4];
    k5_frag_loads(lds, sb, aoff, boff, a, b);

    __builtin_amdgcn_s_setprio(1);
#pragma unroll
    for (int u = 0; u < 8; ++u)
#pragma unroll
        for (int s = 0; s < 4; ++s)
            acc[u][s] = __builtin_amdgcn_mfma_f32_16x16x32_bf16(a[u], b[s], acc[u][s], 0, 0, 0);
    __builtin_amdgcn_s_setprio(0);

    asm volatile("s_waitcnt lgkmcnt(0)" ::: "memory");
    __builtin_amdgcn_sched_barrier(0);
    __builtin_amdgcn_s_barrier();

    if constexpr (DO_STAGE) {
        const int ko = (t + 4) * 32;
        async_copy16(lds + sb + ldsA0,         gA0 + ko);
        async_copy16(lds + sb + ldsA1,         gA1 + ko);
        async_copy16(lds + sb + 16384 + ldsA0, gB0 + ko);
        async_copy16(lds + sb + 16384 + ldsA1, gB1 + ko);
    }
}

__global__ void __launch_bounds__(512, 2) geo_k5_gemm(const __hip_bfloat16* __restrict__ A,
                                                      const __hip_bfloat16* __restrict__ B,
                                                      float* __restrict__ C) {
    __shared__ alignas(16) char lds[131072];   // 4 slots x (A 16K + B 16K)
    const int tid = threadIdx.x;               // 512
    const int l = tid & 63, w = tid >> 6;

    // bijective XCD remap: 512 blocks = 8 xcds x (16 mtiles x 4 ntiles)
    const int bid = blockIdx.x;
    const int xcd = bid & 7;
    const int loc = bid >> 3;                  // 0..63, temporal order on XCD
    const int m0  = (xcd * 16 + (loc >> 2)) * 256;
    const int n0  = (loc & 3) * 256;

    // ---- staging constants: wave-instr (w,j) covers 16 rows x 32 k-elems.
    // lane l -> local row (l>>2), chunk (l&3); global col pre-swizzled so the
    // linear LDS dest at row r, chunk c holds global chunk c ^ ((r>>1)&3).
    const int swz   = (((l & 3) ^ ((l >> 3) & 3)) * 8);   // elems
    const int rloc0 = w * 32 + (l >> 2);
    const int rloc1 = rloc0 + 16;
    const __hip_bfloat16* gA0 = A + (size_t)(m0 + rloc0) * IN_DIM + swz;
    const __hip_bfloat16* gA1 = A + (size_t)(m0 + rloc1) * IN_DIM + swz;
    const __hip_bfloat16* gB0 = B + (size_t)(n0 + rloc0) * IN_DIM + swz;
    const __hip_bfloat16* gB1 = B + (size_t)(n0 + rloc1) * IN_DIM + swz;
    const int ldsA0 = w * 2048 + l * 16;
    const int ldsA1 = ldsA0 + 1024;

    // ---- fragment-read constants (iteration-invariant, imm-offset walk)
    const int lane15 = l & 15;
    const int s_r    = (lane15 >> 1) & 3;
    const int rdch   = ((l >> 4) ^ s_r) * 16;             // bytes
    const int wmoff  = (w >> 2) * 128;                    // wave M offset
    const int wnoff  = (w & 3) * 64;                      // wave N offset
    const int aoff   = (wmoff + lane15) * 64 + rdch;
    const int boff   = 16384 + (wnoff + lane15) * 64 + rdch;

    f32x4 acc[8][4];
#pragma unroll
    for (int u = 0; u < 8; ++u)
#pragma unroll
        for (int s = 0; s < 4; ++s) acc[u][s] = (f32x4){0.f, 0.f, 0.f, 0.f};

    // prologue: stage k-tiles 0..3 into slots 0..3 (16 loads in flight)
#pragma unroll
    for (int p = 0; p < 4; ++p) {
        const int sb = p * 32768;
        const int ko = p * 32;
        async_copy16(lds + sb + ldsA0,         gA0 + ko);
        async_copy16(lds + sb + ldsA1,         gA1 + ko);
        async_copy16(lds + sb + 16384 + ldsA0, gB0 + ko);
        async_copy16(lds + sb + 16384 + ldsA1, gB1 + ko);
    }

    // main loop: 16 k-tiles of BK=32 (K=512)
    for (int t = 0; t < 12; ++t)
        k5_step<12, true>(lds, t, gA0, gA1, gB0, gB1, ldsA0, ldsA1, aoff, boff, acc);
    k5_step<12, false>(lds, 12, gA0, gA1, gB0, gB1, ldsA0, ldsA1, aoff, boff, acc);
    k5_step<8,  false>(lds, 13, gA0, gA1, gB0, gB1, ldsA0, ldsA1, aoff, boff, acc);
    k5_step<4,  false>(lds, 14, gA0, gA1, gB0, gB1, ldsA0, ldsA1, aoff, boff, acc);
    k5_step<0,  false>(lds, 15, gA0, gA1, gB0, gB1, ldsA0, ldsA1, aoff, boff, acc);

    // epilogue: C/D layout col = lane&15, row = (lane>>4)*4 + v  [m89]
    const int cm = m0 + wmoff + (l >> 4) * 4;
    const int cn = n0 + wnoff + lane15;
#pragma unroll
    for (int u = 0; u < 8; ++u)
#pragma unroll
        for (int s = 0; s < 4; ++s)
#pragma unroll
            for (int v = 0; v < 4; ++v)
                C[(size_t)(cm + u * 16 + v) * OUT_DIM + cn + s * 16] = acc[u][s][v];
}

extern "C" void kernel_launch(void* const* d_in, const int* in_sizes, int n_in,
                              void* d_out, int out_size, void* d_ws, size_t ws_size,
                              hipStream_t stream) {
    const float* x  = (const float*)d_in[0];
    const float* U0 = (const float*)d_in[1];
    const float* Wa = (const float*)d_in[2];
    const float* La = (const float*)d_in[3];
    const float* Ra = (const float*)d_in[4];
    const float* Wb = (const float*)d_in[5];
    const float* Lb = (const float*)d_in[6];
    const float* Rb = (const float*)d_in[7];
    float* out = (float*)d_out;

    char* ws = (char*)d_ws;
    unsigned short* xh  = (unsigned short*)(ws);             // 33,554,432 B
    unsigned short* wh  = (unsigned short*)(ws + 33554432);  //  1,048,576 B
    float* part = (float*)(ws + 34603008);                   //     65,536 B
    float* Vws  = (float*)(ws + 34668544);                   //     32,768 B
    float* Lbp  = (float*)(ws + 34701312);                   //     16,384 B
    float* RRws = (float*)(ws + 34717696);                   //     16,384 B
    float* VPws = (float*)(ws + 34734080);                   //     32,768 B

    geo_k1<<<1024, 256, 0, stream>>>(x, xh, Wa, Wb, part);
    geo_k2<<<1, 256, 0, stream>>>(part, La, Ra, Lb, Rb, Vws, Lbp, VPws, RRws);
    geo_k34<<<1024, 256, 0, stream>>>(U0, Vws, VPws, Lbp, RRws, wh);
    geo_k5_gemm<<<512, 512, 0, stream>>>((const __hip_bfloat16*)xh,
                                         (const __hip_bfloat16*)wh, out);
}

// Round 3
// 263.295 us; speedup vs baseline: 1.0358x; 1.0358x over previous
//
#include <hip/hip_runtime.h>
#include <hip/hip_bf16.h>
#include <type_traits>
#include <cstdint>

// Problem constants
#define IN_DIM   512
#define OUT_DIM  1024
#define MROWS    32768    // 8 * 4096

typedef float f32x4 __attribute__((ext_vector_type(4)));
typedef short s8vec __attribute__((ext_vector_type(8)));
typedef __bf16 b8vec __attribute__((ext_vector_type(8)));

template <typename V, typename = void>
struct mfma_ok : std::false_type {};
template <typename V>
struct mfma_ok<V, std::void_t<decltype(__builtin_amdgcn_mfma_f32_16x16x32_bf16(
    std::declval<V>(), std::declval<V>(), std::declval<f32x4>(), 0, 0, 0))>>
    : std::true_type {};
using frag_t = std::conditional_t<mfma_ok<s8vec>::value, s8vec, b8vec>;

__device__ __forceinline__ void async_copy16(void* lds, const void* g) {
    __builtin_amdgcn_global_load_lds(
        (const __attribute__((address_space(1))) void*)(uintptr_t)g,
        (__attribute__((address_space(3))) void*)(uint32_t)(uintptr_t)lds,
        16, 0, 0);
}

__device__ __forceinline__ unsigned short f2bf(float f) {
    unsigned int u = __float_as_uint(f);
    unsigned int r = (u + 0x7fffu + ((u >> 16) & 1u)) >> 16;
    return (unsigned short)r;
}

// ---------------- K1: bf16 cast + fused z@Wa / z@Wb per-block partials -----
// grid 1024 x 256; block handles 32 rows. thread: 4 cols (float4), 16 rows.
__global__ void __launch_bounds__(256) geo_k1(const float* __restrict__ x,
                                              unsigned short* __restrict__ xh,
                                              const float* __restrict__ Wa,
                                              const float* __restrict__ Wb,
                                              float* __restrict__ part) {
    const int tid  = threadIdx.x;
    const int c4   = (tid & 127) * 4;
    const int half = tid >> 7;
    const int r0   = blockIdx.x * 32 + half * 16;
    float4 s = {0.f, 0.f, 0.f, 0.f};
    for (int i = 0; i < 16; ++i) {
        const size_t base = (size_t)(r0 + i) * IN_DIM + c4;
        float4 v = *(const float4*)(x + base);
        s.x += v.x; s.y += v.y; s.z += v.z; s.w += v.w;
        ushort4 h;
        h.x = f2bf(v.x); h.y = f2bf(v.y); h.z = f2bf(v.z); h.w = f2bf(v.w);
        *(ushort4*)(xh + base) = h;
    }
    const float* wa = Wa + (size_t)c4 * 8;
    const float* wb = Wb + (size_t)c4 * 8;
    float av[8], bv[8];
#pragma unroll
    for (int r = 0; r < 8; ++r) {
        av[r] = s.x * wa[r] + s.y * wa[8 + r] + s.z * wa[16 + r] + s.w * wa[24 + r];
        bv[r] = s.x * wb[r] + s.y * wb[8 + r] + s.z * wb[16 + r] + s.w * wb[24 + r];
    }
#pragma unroll
    for (int off = 32; off; off >>= 1) {
#pragma unroll
        for (int r = 0; r < 8; ++r) {
            av[r] += __shfl_xor(av[r], off, 64);
            bv[r] += __shfl_xor(bv[r], off, 64);
        }
    }
    __shared__ float wred[4][16];
    const int lane = tid & 63, wave = tid >> 6;
    if (lane == 0) {
#pragma unroll
        for (int r = 0; r < 8; ++r) { wred[wave][r] = av[r]; wred[wave][8 + r] = bv[r]; }
    }
    __syncthreads();
    if (tid < 16)
        part[(size_t)blockIdx.x * 16 + tid] =
            wred[0][tid] + wred[1][tid] + wred[2][tid] + wred[3][tid];
}

// ---------------- K2: merged small algebra, 1 block, vectorized ------------
// Rewrite: LDS-instruction-bound phases replaced by f32x4 register tiling.
//  - G16/Zm: 4x4 outer-product tiles, b128 row reads (16 FMA per 2 LDS instr)
//  - J-matmuls removed: J=[[0,I],[-I,0]] => C2m[i][j] = +-G16[i^8][j^8],
//    X*J folds into sign + (j^8) on the write side.
//  - remaining 16x16 matmuls = row.row dots (G16 symmetric; CpT/XiT/CtT/EmT
//    maintained at write time), [16][20] padding kills read bank conflicts.
// Numerics: only f32 summation order changes (safe vs 0.0156 absmax scale).
__device__ __forceinline__ float rowdot16(const float* a, const float* b) {
    float s = 0.f;
#pragma unroll
    for (int c = 0; c < 4; ++c) {
        f32x4 av = *(const f32x4*)(a + 4 * c);
        f32x4 bv = *(const f32x4*)(b + 4 * c);
        s += av[0] * bv[0] + av[1] * bv[1] + av[2] * bv[2] + av[3] * bv[3];
    }
    return s;
}

__global__ void __launch_bounds__(256) geo_k2(const float* __restrict__ part,
                                              const float* __restrict__ La,
                                              const float* __restrict__ Ra,
                                              const float* __restrict__ Lb,
                                              const float* __restrict__ Rb,
                                              float* __restrict__ Vws,
                                              float* __restrict__ Lbp,
                                              float* __restrict__ VPws,
                                              float* __restrict__ RRws) {
    __shared__ __align__(16) float sV[IN_DIM][16];    // 32 KB
    __shared__ __align__(16) float sRb[IN_DIM][8];    // 16 KB
    __shared__ __align__(16) float scratch[8192];     // 32 KB (redp/G16/Zm partials)
    __shared__ __align__(16) float red2[16][16];
    __shared__ float gs[16];
    __shared__ __align__(16) float G16[16][20], C2m[16][20], C3m[16][20], C4m[16][20];
    __shared__ __align__(16) float Cp[16][20], CpT[16][20], Cq[16][20];
    __shared__ __align__(16) float Pi[16][20], Xi[16][20], XiT[16][20];
    __shared__ __align__(16) float T1m[16][20], CtT[16][20];
    __shared__ __align__(16) float Zm[8][16];
    __shared__ __align__(16) float EmT[16][8];
    const int tid = threadIdx.x;  // 256
    const int i = tid >> 4, j = tid & 15;

    // phase 0: reduce part[1024][16] -> gs (vectorized f32x4)
    {
        const float4* p4 = (const float4*)part;   // 4096 float4s
        float4 a = {0.f, 0.f, 0.f, 0.f};
#pragma unroll
        for (int q = 0; q < 16; ++q) {
            float4 v = p4[tid + 256 * q];
            a.x += v.x; a.y += v.y; a.z += v.z; a.w += v.w;
        }
        // partial for row-class tid>>2 (rows (tid>>2)+64q), col group (tid&3)*4
        *(float4*)&scratch[(tid >> 2) * 16 + (tid & 3) * 4] = a;
    }
    __syncthreads();
    {
        const int c = tid >> 4, u = tid & 15;
        float s = 0.f;
#pragma unroll
        for (int q = 0; q < 4; ++q) s += scratch[(c * 4 + q) * 16 + u];
        red2[c][u] = s;
    }
    __syncthreads();
    if (tid < 16) {
        float s = 0.f;
#pragma unroll
        for (int c = 0; c < 16; ++c) s += red2[c][tid];
        gs[tid] = s * (1.0f / 32768.0f);
    }
    __syncthreads();

    // phase 1: build sV = [gs.*La | Ra], sRb, Lbp (global), Vws (global)
#pragma unroll
    for (int rr = 0; rr < 2; ++rr) {
        const int row = tid * 2 + rr;
        float4 la0 = *(const float4*)(La + row * 8);
        float4 la1 = *(const float4*)(La + row * 8 + 4);
        float4 ra0 = *(const float4*)(Ra + row * 8);
        float4 ra1 = *(const float4*)(Ra + row * 8 + 4);
        float4 rb0 = *(const float4*)(Rb + row * 8);
        float4 rb1 = *(const float4*)(Rb + row * 8 + 4);
        float4 lb0 = *(const float4*)(Lb + row * 8);
        float4 lb1 = *(const float4*)(Lb + row * 8 + 4);
        float4 v0 = {gs[0] * la0.x, gs[1] * la0.y, gs[2] * la0.z, gs[3] * la0.w};
        float4 v1 = {gs[4] * la1.x, gs[5] * la1.y, gs[6] * la1.z, gs[7] * la1.w};
        *(float4*)&sV[row][0]  = v0;
        *(float4*)&sV[row][4]  = v1;
        *(float4*)&sV[row][8]  = ra0;
        *(float4*)&sV[row][12] = ra1;
        *(float4*)(Vws + row * 16)      = v0;
        *(float4*)(Vws + row * 16 + 4)  = v1;
        *(float4*)(Vws + row * 16 + 8)  = ra0;
        *(float4*)(Vws + row * 16 + 12) = ra1;
        *(float4*)&sRb[row][0] = rb0;
        *(float4*)&sRb[row][4] = rb1;
        float4 l0 = {gs[8] * lb0.x,  gs[9] * lb0.y,  gs[10] * lb0.z, gs[11] * lb0.w};
        float4 l1 = {gs[12] * lb1.x, gs[13] * lb1.y, gs[14] * lb1.z, gs[15] * lb1.w};
        *(float4*)(Lbp + row * 8)     = l0;
        *(float4*)(Lbp + row * 8 + 4) = l1;
    }
    __syncthreads();

    // phase 2: G16 = V^T V and Zm = Rb^T V via 4x4 register tiles
    {
        // G16 partials: 16 slices (32 k each) x 16 (bi,bj) blocks
        const int ks = tid >> 4, blk = tid & 15, bi = blk >> 2, bj = blk & 3;
        float acc[4][4] = {};
        for (int q = 0; q < 32; ++q) {
            const int k = ks * 32 + ((q + ks) & 31);   // rotation: breaks bank alias
            f32x4 a = *(const f32x4*)&sV[k][bi * 4];
            f32x4 b = *(const f32x4*)&sV[k][bj * 4];
#pragma unroll
            for (int r = 0; r < 4; ++r)
#pragma unroll
                for (int c = 0; c < 4; ++c) acc[r][c] += a[r] * b[c];
        }
#pragma unroll
        for (int r = 0; r < 4; ++r) {
            f32x4 t = {acc[r][0], acc[r][1], acc[r][2], acc[r][3]};
            *(f32x4*)&scratch[ks * 256 + (bi * 4 + r) * 16 + bj * 4] = t;
        }
        // Zm partials: 32 slices (16 k each) x 8 (zbi,zbj) blocks
        const int zks = tid >> 3, zblk = tid & 7, zbi = zblk >> 2, zbj = zblk & 3;
        float zacc[4][4] = {};
        for (int q = 0; q < 16; ++q) {
            const int k = zks * 16 + ((q + zks) & 15);
            f32x4 a = *(const f32x4*)&sRb[k][zbi * 4];
            f32x4 b = *(const f32x4*)&sV[k][zbj * 4];
#pragma unroll
            for (int r = 0; r < 4; ++r)
#pragma unroll
                for (int c = 0; c < 4; ++c) zacc[r][c] += a[r] * b[c];
        }
#pragma unroll
        for (int r = 0; r < 4; ++r) {
            f32x4 t = {zacc[r][0], zacc[r][1], zacc[r][2], zacc[r][3]};
            *(f32x4*)&scratch[4096 + zks * 128 + (zbi * 4 + r) * 16 + zbj * 4] = t;
        }
    }
    __syncthreads();
    {
        float s = 0.f;
#pragma unroll
        for (int ks = 0; ks < 16; ++ks) s += scratch[ks * 256 + i * 16 + j];
        G16[i][j] = s;
    }
    if (tid < 128) {
        const int r = tid >> 4, u = tid & 15;
        float s = 0.f;
#pragma unroll
        for (int ks = 0; ks < 32; ++ks) s += scratch[4096 + ks * 128 + r * 16 + u];
        Zm[r][u] = s;
    }
    __syncthreads();

    // phase 3: RK4 core chain, J folded algebraically
    C2m[i][j] = (((i ^ j) & 8) ? 1.f : -1.f) * G16[i ^ 8][j ^ 8];
    __syncthreads();
    {   // C3m = (C2m*G16)*J : write-side fold
        float s = rowdot16(&C2m[i][0], &G16[j][0]);
        C3m[i][j ^ 8] = (j < 8) ? s : -s;
    }
    __syncthreads();
    {   // C4m = (C3m*G16)*J
        float s = rowdot16(&C3m[i][0], &G16[j][0]);
        C4m[i][j ^ 8] = (j < 8) ? s : -s;
    }
    __syncthreads();

    const float h  = 0.125f;
    const float c1 = h, c2 = h * h * 0.5f, c3 = h * h * h * (1.f / 6.f),
                c4 = h * h * h * h * (1.f / 24.f);
    {
        const float jm = (j == (i ^ 8)) ? ((i < 8) ? 1.f : -1.f) : 0.f;
        const float cp = c1 * jm + c2 * C2m[i][j] + c3 * C3m[i][j] + c4 * C4m[i][j];
        const float cq = c2 * jm + c3 * C2m[i][j] + c4 * C3m[i][j];
        Cp[i][j] = cp; CpT[j][i] = cp; Cq[i][j] = cq;
        Xi[i][j] = 0.f; XiT[i][j] = 0.f;
        Pi[i][j] = cp;
    }
    __syncthreads();

    for (int it = 0; it < 7; ++it) {
        T1m[i][j] = rowdot16(&Pi[i][0], &G16[j][0]);   // T1 = Pi*G16 (G16 sym)
        __syncthreads();
        const float t2  = rowdot16(&T1m[i][0], &CpT[j][0]);  // T2 = T1*Cp
        const float pij = Pi[i][j];
        Xi[i][j] += pij; XiT[j][i] += pij;
        Pi[i][j] = pij + Cp[i][j] + t2;
        __syncthreads();
    }

    T1m[i][j] = rowdot16(&Cq[i][0], &G16[j][0]);       // T1 = Cq*G16
    __syncthreads();
    {
        const float t2 = rowdot16(&T1m[i][0], &XiT[j][0]);   // T2 = T1*Xi
        const float ct = 8.f * Cq[i][j] + h * Xi[i][j] + t2;
        CtT[j][i] = ct;
    }
    __syncthreads();

    // EmT[u][r] = (Zm * Ct)[r][u]
    if (tid < 128) {
        const int r = tid >> 4, u = tid & 15;
        EmT[u][r] = rowdot16(&Zm[r][0], &CtT[u][0]);
    }
    __syncthreads();

    // phase 4: VP = V @ Pi (512x16); RR[r][j] = Rb[j][r] + sum_u Em[r][u] V[j][u]
    {
        const int row0 = tid * 2, row1 = row0 + 1;
        float v0a[16], v1a[16];
#pragma unroll
        for (int c = 0; c < 4; ++c) {
            f32x4 t0 = *(const f32x4*)&sV[row0][c * 4];
            f32x4 t1 = *(const f32x4*)&sV[row1][c * 4];
#pragma unroll
            for (int q = 0; q < 4; ++q) { v0a[c * 4 + q] = t0[q]; v1a[c * 4 + q] = t1[q]; }
        }
        float o0[16] = {}, o1[16] = {};
#pragma unroll
        for (int k = 0; k < 16; ++k) {
            f32x4 p0 = *(const f32x4*)&Pi[k][0];
            f32x4 p1 = *(const f32x4*)&Pi[k][4];
            f32x4 p2 = *(const f32x4*)&Pi[k][8];
            f32x4 p3 = *(const f32x4*)&Pi[k][12];
            const float a = v0a[k], b = v1a[k];
#pragma unroll
            for (int q = 0; q < 4; ++q) {
                o0[q]      += a * p0[q];  o1[q]      += b * p0[q];
                o0[4 + q]  += a * p1[q];  o1[4 + q]  += b * p1[q];
                o0[8 + q]  += a * p2[q];  o1[8 + q]  += b * p2[q];
                o0[12 + q] += a * p3[q];  o1[12 + q] += b * p3[q];
            }
        }
#pragma unroll
        for (int c = 0; c < 4; ++c) {
            f32x4 w0 = {o0[c * 4], o0[c * 4 + 1], o0[c * 4 + 2], o0[c * 4 + 3]};
            f32x4 w1 = {o1[c * 4], o1[c * 4 + 1], o1[c * 4 + 2], o1[c * 4 + 3]};
            *(f32x4*)(VPws + row0 * 16 + c * 4) = w0;
            *(f32x4*)(VPws + row1 * 16 + c * 4) = w1;
        }
        float s0[8], s1[8];
#pragma unroll
        for (int c = 0; c < 2; ++c) {
            f32x4 t0 = *(const f32x4*)&sRb[row0][c * 4];
            f32x4 t1 = *(const f32x4*)&sRb[row1][c * 4];
#pragma unroll
            for (int q = 0; q < 4; ++q) { s0[c * 4 + q] = t0[q]; s1[c * 4 + q] = t1[q]; }
        }
#pragma unroll
        for (int u = 0; u < 16; ++u) {
            f32x4 e0 = *(const f32x4*)&EmT[u][0];
            f32x4 e1 = *(const f32x4*)&EmT[u][4];
            const float a = v0a[u], b = v1a[u];
#pragma unroll
            for (int r = 0; r < 4; ++r) {
                s0[r]     += a * e0[r];  s1[r]     += b * e0[r];
                s0[4 + r] += a * e1[r];  s1[4 + r] += b * e1[r];
            }
        }
#pragma unroll
        for (int r = 0; r < 8; ++r) {
            RRws[r * IN_DIM + row0] = s0[r];
            RRws[r * IN_DIM + row1] = s1[r];
        }
    }
}

// ---------------- K34: W row = U0 + (U0.VP) V^T + [0; Lbp RR] -> bf16 ------
__global__ void __launch_bounds__(256) geo_k34(const float* __restrict__ U0,
                                               const float* __restrict__ Vws,
                                               const float* __restrict__ VPws,
                                               const float* __restrict__ Lbp,
                                               const float* __restrict__ RRws,
                                               unsigned short* __restrict__ wh) {
    const int o   = blockIdx.x;
    const int tid = threadIdx.x;
    const int j0  = tid * 2;
    const float2 u0 = *(const float2*)(U0 + (size_t)o * IN_DIM + j0);

    const float* vpa = VPws + j0 * 16;
    const float* vpb = vpa + 16;
    float p[16];
#pragma unroll
    for (int u = 0; u < 16; ++u) p[u] = u0.x * vpa[u] + u0.y * vpb[u];
#pragma unroll
    for (int off = 32; off; off >>= 1) {
#pragma unroll
        for (int u = 0; u < 16; ++u) p[u] += __shfl_xor(p[u], off, 64);
    }
    __shared__ float wred[4][16];
    __shared__ float sY[16];
    const int lane = tid & 63, wave = tid >> 6;
    if (lane == 0) {
#pragma unroll
        for (int u = 0; u < 16; ++u) wred[wave][u] = p[u];
    }
    __syncthreads();
    if (tid < 16) sY[tid] = wred[0][tid] + wred[1][tid] + wred[2][tid] + wred[3][tid];
    __syncthreads();

    const float* va = Vws + j0 * 16;
    const float* vb = va + 16;
    float w0 = u0.x, w1 = u0.y;
#pragma unroll
    for (int u = 0; u < 16; ++u) {
        const float s = sY[u];
        w0 += s * va[u];
        w1 += s * vb[u];
    }
    if (o >= IN_DIM) {
        const int op = o - IN_DIM;
#pragma unroll
        for (int r = 0; r < 8; ++r) {
            const float lb = Lbp[op * 8 + r];
            w0 += lb * RRws[r * IN_DIM + j0];
            w1 += lb * RRws[r * IN_DIM + j0 + 1];
        }
    }
    ushort2 hv;
    hv.x = f2bf(w0); hv.y = f2bf(w1);
    *(ushort2*)(wh + (size_t)o * IN_DIM + j0) = hv;
}

// ---------------- K5: out = xh @ wh^T, deep-pipelined 256x256 MFMA ---------
// T3+T4 counted-vmcnt pipeline, 4 LDS slots (BK=32), prefetch distance 3.
// T2 swizzle on the global source side; T1 bijective XCD remap.
__device__ __forceinline__ void k5_frag_loads(const char* lds, int sb, int aoff, int boff,
                                              frag_t (&a)[8], frag_t (&b)[4]) {
#pragma unroll
    for (int u = 0; u < 8; ++u)
        a[u] = *(const frag_t*)(lds + sb + aoff + u * 1024);
#pragma unroll
    for (int s = 0; s < 4; ++s)
        b[s] = *(const frag_t*)(lds + sb + boff + s * 1024);
}

template <int VM, bool DO_STAGE>
__device__ __forceinline__ void k5_step(char* lds, int t,
                                        const __hip_bfloat16* gA0, const __hip_bfloat16* gA1,
                                        const __hip_bfloat16* gB0, const __hip_bfloat16* gB1,
                                        int ldsA0, int ldsA1, int aoff, int boff,
                                        f32x4 (&acc)[8][4]) {
    if constexpr (VM == 12)     asm volatile("s_waitcnt vmcnt(12)" ::: "memory");
    else if constexpr (VM == 8) asm volatile("s_waitcnt vmcnt(8)"  ::: "memory");
    else if constexpr (VM == 4) asm volatile("s_waitcnt vmcnt(4)"  ::: "memory");
    else                        asm volatile("s_waitcnt vmcnt(0)"  ::: "memory");
    __builtin_amdgcn_s_barrier();
    __builtin_amdgcn_sched_barrier(0);

    const int sb = (t & 3) * 32768;
    frag_t a[8], b[4];
    k5_frag_loads(lds, sb, aoff, boff, a, b);

    __builtin_amdgcn_s_setprio(1);
#pragma unroll
    for (int u = 0; u < 8; ++u)
#pragma unroll
        for (int s = 0; s < 4; ++s)
            acc[u][s] = __builtin_amdgcn_mfma_f32_16x16x32_bf16(a[u], b[s], acc[u][s], 0, 0, 0);
    __builtin_amdgcn_s_setprio(0);

    asm volatile("s_waitcnt lgkmcnt(0)" ::: "memory");
    __builtin_amdgcn_sched_barrier(0);
    __builtin_amdgcn_s_barrier();

    if constexpr (DO_STAGE) {
        const int ko = (t + 4) * 32;
        async_copy16(lds + sb + ldsA0,         gA0 + ko);
        async_copy16(lds + sb + ldsA1,         gA1 + ko);
        async_copy16(lds + sb + 16384 + ldsA0, gB0 + ko);
        async_copy16(lds + sb + 16384 + ldsA1, gB1 + ko);
    }
}

__global__ void __launch_bounds__(512, 2) geo_k5_gemm(const __hip_bfloat16* __restrict__ A,
                                                      const __hip_bfloat16* __restrict__ B,
                                                      float* __restrict__ C) {
    __shared__ alignas(16) char lds[131072];   // 4 slots x (A 16K + B 16K)
    const int tid = threadIdx.x;               // 512
    const int l = tid & 63, w = tid >> 6;

    // bijective XCD remap: 512 blocks = 8 xcds x (16 mtiles x 4 ntiles)
    const int bid = blockIdx.x;
    const int xcd = bid & 7;
    const int loc = bid >> 3;                  // 0..63, temporal order on XCD
    const int m0  = (xcd * 16 + (loc >> 2)) * 256;
    const int n0  = (loc & 3) * 256;

    const int swz   = (((l & 3) ^ ((l >> 3) & 3)) * 8);   // elems
    const int rloc0 = w * 32 + (l >> 2);
    const int rloc1 = rloc0 + 16;
    const __hip_bfloat16* gA0 = A + (size_t)(m0 + rloc0) * IN_DIM + swz;
    const __hip_bfloat16* gA1 = A + (size_t)(m0 + rloc1) * IN_DIM + swz;
    const __hip_bfloat16* gB0 = B + (size_t)(n0 + rloc0) * IN_DIM + swz;
    const __hip_bfloat16* gB1 = B + (size_t)(n0 + rloc1) * IN_DIM + swz;
    const int ldsA0 = w * 2048 + l * 16;
    const int ldsA1 = ldsA0 + 1024;

    const int lane15 = l & 15;
    const int s_r    = (lane15 >> 1) & 3;
    const int rdch   = ((l >> 4) ^ s_r) * 16;             // bytes
    const int wmoff  = (w >> 2) * 128;                    // wave M offset
    const int wnoff  = (w & 3) * 64;                      // wave N offset
    const int aoff   = (wmoff + lane15) * 64 + rdch;
    const int boff   = 16384 + (wnoff + lane15) * 64 + rdch;

    f32x4 acc[8][4];
#pragma unroll
    for (int u = 0; u < 8; ++u)
#pragma unroll
        for (int s = 0; s < 4; ++s) acc[u][s] = (f32x4){0.f, 0.f, 0.f, 0.f};

    // prologue: stage k-tiles 0..3 into slots 0..3 (16 loads in flight)
#pragma unroll
    for (int p = 0; p < 4; ++p) {
        const int sb = p * 32768;
        const int ko = p * 32;
        async_copy16(lds + sb + ldsA0,         gA0 + ko);
        async_copy16(lds + sb + ldsA1,         gA1 + ko);
        async_copy16(lds + sb + 16384 + ldsA0, gB0 + ko);
        async_copy16(lds + sb + 16384 + ldsA1, gB1 + ko);
    }

    // main loop: 16 k-tiles of BK=32 (K=512)
    for (int t = 0; t < 12; ++t)
        k5_step<12, true>(lds, t, gA0, gA1, gB0, gB1, ldsA0, ldsA1, aoff, boff, acc);
    k5_step<12, false>(lds, 12, gA0, gA1, gB0, gB1, ldsA0, ldsA1, aoff, boff, acc);
    k5_step<8,  false>(lds, 13, gA0, gA1, gB0, gB1, ldsA0, ldsA1, aoff, boff, acc);
    k5_step<4,  false>(lds, 14, gA0, gA1, gB0, gB1, ldsA0, ldsA1, aoff, boff, acc);
    k5_step<0,  false>(lds, 15, gA0, gA1, gB0, gB1, ldsA0, ldsA1, aoff, boff, acc);

    // epilogue: C/D layout col = lane&15, row = (lane>>4)*4 + v  [m89]
    const int cm = m0 + wmoff + (l >> 4) * 4;
    const int cn = n0 + wnoff + lane15;
#pragma unroll
    for (int u = 0; u < 8; ++u)
#pragma unroll
        for (int s = 0; s < 4; ++s)
#pragma unroll
            for (int v = 0; v < 4; ++v)
                C[(size_t)(cm + u * 16 + v) * OUT_DIM + cn + s * 16] = acc[u][s][v];
}

extern "C" void kernel_launch(void* const* d_in, const int* in_sizes, int n_in,
                              void* d_out, int out_size, void* d_ws, size_t ws_size,
                              hipStream_t stream) {
    const float* x  = (const float*)d_in[0];
    const float* U0 = (const float*)d_in[1];
    const float* Wa = (const float*)d_in[2];
    const float* La = (const float*)d_in[3];
    const float* Ra = (const float*)d_in[4];
    const float* Wb = (const float*)d_in[5];
    const float* Lb = (const float*)d_in[6];
    const float* Rb = (const float*)d_in[7];
    float* out = (float*)d_out;

    char* ws = (char*)d_ws;
    unsigned short* xh  = (unsigned short*)(ws);             // 33,554,432 B
    unsigned short* wh  = (unsigned short*)(ws + 33554432);  //  1,048,576 B
    float* part = (float*)(ws + 34603008);                   //     65,536 B
    float* Vws  = (float*)(ws + 34668544);                   //     32,768 B
    float* Lbp  = (float*)(ws + 34701312);                   //     16,384 B
    float* RRws = (float*)(ws + 34717696);                   //     16,384 B
    float* VPws = (float*)(ws + 34734080);                   //     32,768 B

    geo_k1<<<1024, 256, 0, stream>>>(x, xh, Wa, Wb, part);
    geo_k2<<<1, 256, 0, stream>>>(part, La, Ra, Lb, Rb, Vws, Lbp, VPws, RRws);
    geo_k34<<<1024, 256, 0, stream>>>(U0, Vws, VPws, Lbp, RRws, wh);
    geo_k5_gemm<<<512, 512, 0, stream>>>((const __hip_bfloat16*)xh,
                                         (const __hip_bfloat16*)wh, out);
}